// Round 2
// 748.204 us; speedup vs baseline: 1.1419x; 1.1419x over previous
//
#include <hip/hip_runtime.h>
#include <hip/hip_bf16.h>
#include <hip/hip_fp16.h>

#define L_ATOMS 2048
#define N_TOK 512
#define CA 128
#define CP 16
#define CT 384
#define NBLK 3
#define NHEAD 4
#define HDIM 32
#define FFD 512
#define F1D 388

typedef _Float16 half8 __attribute__((ext_vector_type(8)));
typedef _Float16 half4_t __attribute__((ext_vector_type(4)));
typedef float f32x4 __attribute__((ext_vector_type(4)));

// ---------------------------------------------------------------------------
// C_L = feat @ W_in ; Q init = C_L ; csl = relu(C_L)@W_sl ; csm = relu(C_L)@W_sm
__global__ __launch_bounds__(256) void k_cl(
    const float* __restrict__ pos, const float* __restrict__ charge,
    const float* __restrict__ elem, const float* __restrict__ chars,
    const float* __restrict__ W_in, const float* __restrict__ W_sl,
    const float* __restrict__ W_sm,
    float* __restrict__ out_cl, float* __restrict__ out_q,
    float* __restrict__ csl, float* __restrict__ csm) {
  __shared__ float feat_s[8][F1D];
  __shared__ float rcl_s[8][CA];
  const int t = threadIdx.x;
  const int l0 = blockIdx.x * 8;
  if (t < 24) feat_s[t / 3][t % 3] = pos[l0 * 3 + t];
  else if (t < 32) feat_s[t - 24][3] = charge[l0 + t - 24];
  for (int k = 0; k < 4; k++) {
    int idx = t + k * 256;
    feat_s[idx >> 7][4 + (idx & 127)] = elem[l0 * 128 + idx];
  }
  for (int k = 0; k < 8; k++) {
    int idx = t + k * 256;
    feat_s[idx >> 8][132 + (idx & 255)] = chars[l0 * 256 + idx];
  }
  __syncthreads();
  const int c = t & 127, rh = t >> 7;
  float acc[4] = {0.f, 0.f, 0.f, 0.f};
  for (int f4 = 0; f4 < F1D; f4 += 4) {  // 388 % 4 == 0
    float w0 = W_in[(f4 + 0) * CA + c];
    float w1 = W_in[(f4 + 1) * CA + c];
    float w2 = W_in[(f4 + 2) * CA + c];
    float w3 = W_in[(f4 + 3) * CA + c];
#pragma unroll
    for (int r = 0; r < 4; r++) {
      float4 fv = *(const float4*)&feat_s[rh * 4 + r][f4];
      acc[r] += fv.x * w0 + fv.y * w1 + fv.z * w2 + fv.w * w3;
    }
  }
#pragma unroll
  for (int r = 0; r < 4; r++) {
    int l = l0 + rh * 4 + r;
    out_cl[l * CA + c] = acc[r];
    out_q[l * CA + c] = acc[r];
    rcl_s[rh * 4 + r][c] = fmaxf(acc[r], 0.f);
  }
  __syncthreads();
  const int r = t >> 5, j = t & 15, mat = (t >> 4) & 1;
  const float* W = mat ? W_sm : W_sl;
  float a = 0.f;
  for (int i4 = 0; i4 < CA; i4 += 4) {
    float4 xv = *(const float4*)&rcl_s[r][i4];
    a += xv.x * W[i4 * CP + j] + xv.y * W[(i4 + 1) * CP + j] +
         xv.z * W[(i4 + 2) * CP + j] + xv.w * W[(i4 + 3) * CP + j];
  }
  float* dst = mat ? csm : csl;
  dst[(l0 + r) * CP + j] = a;
}

// ---------------------------------------------------------------------------
// k_pair, MFMA version. Transposed chain: X0=relu(P); X1=relu(W1^T X0);
// X2=relu(W2^T X1); P+=W3^T X2; bias=Wb^T P. All via 16x16x16 f16 MFMA.
// m-side loads hoisted out of the li loop; fast rcp/sqrt for inv-distance.
__global__ __launch_bounds__(256, 4) void k_pair(
    const float* __restrict__ pos, const int* __restrict__ uid,
    const float* __restrict__ csl, const float* __restrict__ csm,
    const float* __restrict__ W_d, const float* __restrict__ W_invd,
    const float* __restrict__ W_vm, const float* __restrict__ Wp1,
    const float* __restrict__ Wp2, const float* __restrict__ Wp3,
    const float* __restrict__ Wb,
    float* __restrict__ P_out, _Float16* __restrict__ bias_hp, int use_bias) {
  __shared__ _Float16 bias_lds[12 * 2 * 256];  // [plane][lrow][m] 12KB
  const int t = threadIdx.x;
  const int w = t >> 6, lane = t & 63;
  const int q = lane >> 4, j16 = lane & 15;
  const int c4 = q * 4;
  const int m_base = blockIdx.x * 256;
  const int l0 = blockIdx.y * 2;
  // weight A-fragments: A[m=j16][k=c4+r]
  half4_t w1f, w2f, w3f, wbf;
#pragma unroll
  for (int r = 0; r < 4; r++) {
    w1f[r] = (_Float16)Wp1[(c4 + r) * 16 + j16];
    w2f[r] = (_Float16)Wp2[(c4 + r) * 16 + j16];
    w3f[r] = (_Float16)Wp3[(c4 + r) * 16 + j16];
  }
  if (j16 < 12) {
    int bb = j16 >> 2, hh = j16 & 3;
#pragma unroll
    for (int r = 0; r < 4; r++)
      wbf[r] = (_Float16)Wb[(bb * 16 + c4 + r) * 4 + hh];
  } else {
    wbf = half4_t{0, 0, 0, 0};
  }
  // geometry weight columns for this lane's 4 channels
  const float4 wdx = *(const float4*)(W_d + c4);
  const float4 wdy = *(const float4*)(W_d + 16 + c4);
  const float4 wdz = *(const float4*)(W_d + 32 + c4);
  const float4 wiv = *(const float4*)(W_invd + c4);
  const float4 wvm = *(const float4*)(W_vm + c4);
  const float4 cl[2] = {*(const float4*)(csl + l0 * 16 + c4),
                        *(const float4*)(csl + (l0 + 1) * 16 + c4)};
  const float plx[2] = {pos[l0 * 3 + 0], pos[(l0 + 1) * 3 + 0]};
  const float ply[2] = {pos[l0 * 3 + 1], pos[(l0 + 1) * 3 + 1]};
  const float plz[2] = {pos[l0 * 3 + 2], pos[(l0 + 1) * 3 + 2]};
  const int uidl[2] = {uid[l0], uid[l0 + 1]};
  const f32x4 z = {0.f, 0.f, 0.f, 0.f};
#pragma unroll
  for (int it = 0; it < 4; it++) {
    const int moff = w * 64 + it * 16 + j16;
    const int m = m_base + moff;
    const float pmx = pos[m * 3 + 0], pmy = pos[m * 3 + 1],
                pmz = pos[m * 3 + 2];
    const int um = uid[m];
    const float4 cm = *(const float4*)(csm + m * 16 + c4);
#pragma unroll
    for (int li = 0; li < 2; li++) {
      const int lg = l0 + li;
      float dx = plx[li] - pmx, dy = ply[li] - pmy, dz = plz[li] - pmz;
      float vfm = (uidl[li] == um) ? 1.f : 0.f;
      float d2 = dx * dx + dy * dy + dz * dz;
      float invd_v =
          vfm * __builtin_amdgcn_rcpf(1.f + __builtin_amdgcn_sqrtf(d2));
      float dxv = dx * vfm, dyv = dy * vfm, dzv = dz * vfm;
      float pv[4];
      pv[0] = dxv * wdx.x + dyv * wdy.x + dzv * wdz.x + invd_v * wiv.x +
              vfm * wvm.x + cl[li].x + cm.x;
      pv[1] = dxv * wdx.y + dyv * wdy.y + dzv * wdz.y + invd_v * wiv.y +
              vfm * wvm.y + cl[li].y + cm.y;
      pv[2] = dxv * wdx.z + dyv * wdy.z + dzv * wdz.z + invd_v * wiv.z +
              vfm * wvm.z + cl[li].z + cm.z;
      pv[3] = dxv * wdx.w + dyv * wdy.w + dzv * wdz.w + invd_v * wiv.w +
              vfm * wvm.w + cl[li].w + cm.w;
      half4_t b0, b1, b2;
#pragma unroll
      for (int r = 0; r < 4; r++) b0[r] = (_Float16)fmaxf(pv[r], 0.f);
      f32x4 d = __builtin_amdgcn_mfma_f32_16x16x16f16(w1f, b0, z, 0, 0, 0);
#pragma unroll
      for (int r = 0; r < 4; r++) b1[r] = (_Float16)fmaxf(d[r], 0.f);
      d = __builtin_amdgcn_mfma_f32_16x16x16f16(w2f, b1, z, 0, 0, 0);
#pragma unroll
      for (int r = 0; r < 4; r++) b2[r] = (_Float16)fmaxf(d[r], 0.f);
      d = __builtin_amdgcn_mfma_f32_16x16x16f16(w3f, b2, z, 0, 0, 0);
      float pf[4];
#pragma unroll
      for (int r = 0; r < 4; r++) pf[r] = pv[r] + d[r];
      *(float4*)(P_out + ((size_t)lg * L_ATOMS + m) * 16 + c4) =
          make_float4(pf[0], pf[1], pf[2], pf[3]);
      if (use_bias) {
        half4_t bf;
#pragma unroll
        for (int r = 0; r < 4; r++) bf[r] = (_Float16)pf[r];
        f32x4 db = __builtin_amdgcn_mfma_f32_16x16x16f16(wbf, bf, z, 0, 0, 0);
        if (q < 3) {
#pragma unroll
          for (int r = 0; r < 4; r++)
            bias_lds[((q * 4 + r) * 2 + li) * 256 + moff] = (_Float16)db[r];
        }
      }
    }
  }
  if (use_bias) {
    __syncthreads();
    const size_t plane = (size_t)L_ATOMS * L_ATOMS;
#pragma unroll
    for (int kk = 0; kk < 3; kk++) {
      int cid = t + kk * 256;           // 768 chunks of 8 halves
      int pl = cid >> 6;                // 12 planes
      int lrow = (cid >> 5) & 1;
      int chunk = cid & 31;
      half8 v = *(const half8*)&bias_lds[(pl * 2 + lrow) * 256 + chunk * 8];
      *(half8*)(bias_hp + pl * plane + (size_t)(l0 + lrow) * L_ATOMS + m_base +
                chunk * 8) = v;
    }
  }
}

// ---------------------------------------------------------------------------
// x = LN(Q); q/k (head-major fp16), v transposed vT[h][d][l] fp16.
// 4 rows/block (grid 512) -> 2 blocks/CU for latency hiding.
__global__ __launch_bounds__(256) void k_lnqkv(
    const float* __restrict__ Qg, const float* __restrict__ Wq,
    const float* __restrict__ Wk, const float* __restrict__ Wv,
    _Float16* __restrict__ q_hd, _Float16* __restrict__ k_hd,
    _Float16* __restrict__ vT_hd) {
  __shared__ float x_s[4][CA];
  const int t = threadIdx.x;
  const int l0 = blockIdx.x * 4;
  if (t < 128) ((float4*)x_s)[t] = ((const float4*)(Qg + l0 * CA))[t];
  __syncthreads();
  if (t < 128) {
    const int r = t >> 5, i = t & 31;
    float s1 = 0.f, s2 = 0.f;
#pragma unroll
    for (int k = 0; k < 4; k++) {
      float x = x_s[r][i + 32 * k];
      s1 += x;
      s2 += x * x;
    }
#pragma unroll
    for (int m = 1; m <= 16; m <<= 1) {
      s1 += __shfl_xor(s1, m);
      s2 += __shfl_xor(s2, m);
    }
    float mu = s1 * (1.f / 128.f);
    float var = s2 * (1.f / 128.f) - mu * mu;
    float inv = 1.f / sqrtf(var + 1e-5f);
#pragma unroll
    for (int k = 0; k < 4; k++)
      x_s[r][i + 32 * k] = (x_s[r][i + 32 * k] - mu) * inv;
  }
  __syncthreads();
  const int c = t & 127, rh = t >> 7;
  const int h = c >> 5, d = c & 31;
#pragma unroll
  for (int mat = 0; mat < 3; mat++) {
    const float* W = mat == 0 ? Wq : (mat == 1 ? Wk : Wv);
    float acc[2] = {0.f, 0.f};
    for (int i4 = 0; i4 < CA; i4 += 4) {
      float w0 = W[(i4 + 0) * CA + c];
      float w1 = W[(i4 + 1) * CA + c];
      float w2 = W[(i4 + 2) * CA + c];
      float w3 = W[(i4 + 3) * CA + c];
#pragma unroll
      for (int rr = 0; rr < 2; rr++) {
        float4 xv = *(const float4*)&x_s[rh * 2 + rr][i4];
        acc[rr] += xv.x * w0 + xv.y * w1 + xv.z * w2 + xv.w * w3;
      }
    }
#pragma unroll
    for (int rr = 0; rr < 2; rr++) {
      int l = l0 + rh * 2 + rr;
      if (mat == 0)
        q_hd[(h * L_ATOMS + l) * HDIM + d] = (_Float16)acc[rr];
      else if (mat == 1)
        k_hd[(h * L_ATOMS + l) * HDIM + d] = (_Float16)acc[rr];
      else
        vT_hd[(h * HDIM + d) * L_ATOMS + l] = (_Float16)acc[rr];
    }
  }
}

// ---------------------------------------------------------------------------
// flash attention, one (16-row l-tile, head) per block; 4 waves split m-range.
// Transposed logits: D = mfma(K, Q) -> D[row=m][col=l]. Per lane (q4,c16):
// logits for l = l0+c16, m = m0+q4*4+r (+16). Bias is then 4 consecutive
// halves along m (one 8B load per fragment). Softmax over m = 7-op local
// tree + shfl_xor(16,32) across quads. p_lds is per-wave: no barriers in
// the main loop (DS ops from one wave complete in order; compiler fences
// prevent reordering).
template <int USE_BIAS>
__global__ __launch_bounds__(256) void k_attn(
    const _Float16* __restrict__ q_hd, const _Float16* __restrict__ k_hd,
    const _Float16* __restrict__ vT_hd, const _Float16* __restrict__ bias_hp,
    const float* __restrict__ Pmat, const float* __restrict__ Wb,
    float* __restrict__ o_buf, int b) {
  __shared__ __align__(16) _Float16 p_lds[4][16][40];  // [wave][l][m]
  __shared__ float o_sh[4][16][33];
  __shared__ float M_sh[4][16];
  __shared__ float S_sh[4][16];
  __shared__ float wb_s[16];
  const int t = threadIdx.x;
  const int w = t >> 6, lane = t & 63;
  const int l0 = blockIdx.x * 16;
  const int h = blockIdx.y;
  if (USE_BIAS == 0) {
    if (t < 16) wb_s[t] = Wb[(b * 16 + t) * 4 + h];
    __syncthreads();
  }
  const int c16 = lane & 15, q4 = lane >> 4;
  // B-operand: q row l = l0 + c16
  half8 qa = *(const half8*)(q_hd + ((h * L_ATOMS + l0 + c16) * HDIM + q4 * 8));
  f32x4 o0 = {0.f, 0.f, 0.f, 0.f}, o1 = {0.f, 0.f, 0.f, 0.f};
  float M = -INFINITY;  // running max for row l = l0+c16 (dup across quads)
  float S = 0.f;
  const float scale = 0.17677669529663687f;  // 1/sqrt(32)
  const _Float16* bias_row =
      bias_hp + ((size_t)(b * 4 + h) * L_ATOMS + (l0 + c16)) * L_ATOMS;
  for (int it = 0; it < 16; it++) {
    const int m0 = w * 512 + it * 32;
    half8 kb0 =
        *(const half8*)(k_hd + ((h * L_ATOMS + m0 + c16) * HDIM + q4 * 8));
    half8 kb1 =
        *(const half8*)(k_hd + ((h * L_ATOMS + m0 + 16 + c16) * HDIM + q4 * 8));
    half8 vb0 =
        *(const half8*)(vT_hd + ((h * HDIM + c16) * L_ATOMS + m0 + q4 * 8));
    half8 vb1 = *(const half8*)(vT_hd +
                                ((h * HDIM + 16 + c16) * L_ATOMS + m0 + q4 * 8));
    f32x4 z = {0.f, 0.f, 0.f, 0.f};
    f32x4 c0 = __builtin_amdgcn_mfma_f32_16x16x32_f16(kb0, qa, z, 0, 0, 0);
    f32x4 c1 = __builtin_amdgcn_mfma_f32_16x16x32_f16(kb1, qa, z, 0, 0, 0);
    float l0v[4], l1v[4];
    if (USE_BIAS) {
      half4_t bh0 = *(const half4_t*)(bias_row + m0 + q4 * 4);
      half4_t bh1 = *(const half4_t*)(bias_row + m0 + 16 + q4 * 4);
#pragma unroll
      for (int r = 0; r < 4; r++) {
        l0v[r] = c0[r] * scale + (float)bh0[r];
        l1v[r] = c1[r] * scale + (float)bh1[r];
      }
    } else {
#pragma unroll
      for (int r = 0; r < 4; r++) {
        const float* Pp0 =
            Pmat + ((size_t)(l0 + c16) * L_ATOMS + m0 + q4 * 4 + r) * 16;
        const float* Pp1 = Pp0 + 16 * 16;
        float a0 = 0.f, a1 = 0.f;
#pragma unroll
        for (int c2 = 0; c2 < 16; c2++) {
          a0 += Pp0[c2] * wb_s[c2];
          a1 += Pp1[c2] * wb_s[c2];
        }
        l0v[r] = c0[r] * scale + a0;
        l1v[r] = c1[r] * scale + a1;
      }
    }
    // online softmax over m for row l = l0+c16
    float tm = fmaxf(fmaxf(fmaxf(l0v[0], l0v[1]), fmaxf(l0v[2], l0v[3])),
                     fmaxf(fmaxf(l1v[0], l1v[1]), fmaxf(l1v[2], l1v[3])));
    tm = fmaxf(tm, __shfl_xor(tm, 16));
    tm = fmaxf(tm, __shfl_xor(tm, 32));
    float Mn = fmaxf(M, tm);
    float al = __expf(M - Mn);
    float p0[4], p1[4], ps = 0.f;
#pragma unroll
    for (int r = 0; r < 4; r++) {
      p0[r] = __expf(l0v[r] - Mn);
      p1[r] = __expf(l1v[r] - Mn);
      ps += p0[r] + p1[r];
    }
    float rs = ps + __shfl_xor(ps, 16);
    rs += __shfl_xor(rs, 32);
    S = S * al + rs;
    M = Mn;
    // P -> LDS [l][m], two 8B stores
    half4_t ph0, ph1;
#pragma unroll
    for (int r = 0; r < 4; r++) {
      ph0[r] = (_Float16)p0[r];
      ph1[r] = (_Float16)p1[r];
    }
    *(half4_t*)&p_lds[w][c16][q4 * 4] = ph0;
    *(half4_t*)&p_lds[w][c16][16 + q4 * 4] = ph1;
    // rescale O rows (row index = q4*4+r) with that row's al
    float alr[4];
#pragma unroll
    for (int r = 0; r < 4; r++) alr[r] = __shfl(al, q4 * 4 + r);
#pragma unroll
    for (int r = 0; r < 4; r++) {
      o0[r] *= alr[r];
      o1[r] *= alr[r];
    }
    asm volatile("" ::: "memory");
    __builtin_amdgcn_sched_barrier(0);
    half8 pa = *(const half8*)(&p_lds[w][c16][q4 * 8]);
    o0 = __builtin_amdgcn_mfma_f32_16x16x32_f16(pa, vb0, o0, 0, 0, 0);
    o1 = __builtin_amdgcn_mfma_f32_16x16x32_f16(pa, vb1, o1, 0, 0, 0);
    asm volatile("" ::: "memory");
    __builtin_amdgcn_sched_barrier(0);
  }
#pragma unroll
  for (int r = 0; r < 4; r++) {
    o_sh[w][q4 * 4 + r][c16] = o0[r];
    o_sh[w][q4 * 4 + r][16 + c16] = o1[r];
  }
  if (q4 == 0) {
    M_sh[w][c16] = M;
    S_sh[w][c16] = S;
  }
  __syncthreads();
  {
    const int d = t & 31, r8 = t >> 5;
#pragma unroll
    for (int k = 0; k < 2; k++) {
      int row = r8 + 8 * k;
      float Mg = fmaxf(fmaxf(M_sh[0][row], M_sh[1][row]),
                       fmaxf(M_sh[2][row], M_sh[3][row]));
      float Sg = 0.f, ov = 0.f;
#pragma unroll
      for (int ww = 0; ww < 4; ww++) {
        float e = __expf(M_sh[ww][row] - Mg);
        Sg += S_sh[ww][row] * e;
        ov += o_sh[ww][row][d] * e;
      }
      o_buf[(l0 + row) * CA + h * HDIM + d] = ov / Sg;
    }
  }
}

// ---------------------------------------------------------------------------
// Q += o@Wo ; y = LN(Q) ; Q += relu(y@Wt1)@Wt2.
// 4 rows/block (grid 512) -> 2 blocks/CU.
__global__ __launch_bounds__(256) void k_ffn(
    float* __restrict__ Qg, const float* __restrict__ o_buf,
    const float* __restrict__ Wo, const float* __restrict__ Wt1,
    const float* __restrict__ Wt2) {
  __shared__ float o_s[4][CA];
  __shared__ float q_s[4][CA];
  __shared__ float h_s[4][FFD];
  const int t = threadIdx.x;
  const int l0 = blockIdx.x * 4;
  if (t < 128) {
    ((float4*)o_s)[t] = ((const float4*)(o_buf + l0 * CA))[t];
    ((float4*)q_s)[t] = ((const float4*)(Qg + l0 * CA))[t];
  }
  __syncthreads();
  const int c = t & 127, rh = t >> 7;
  {
    float acc[2] = {0.f, 0.f};
    for (int i4 = 0; i4 < CA; i4 += 4) {
      float w0 = Wo[(i4 + 0) * CA + c];
      float w1 = Wo[(i4 + 1) * CA + c];
      float w2 = Wo[(i4 + 2) * CA + c];
      float w3 = Wo[(i4 + 3) * CA + c];
#pragma unroll
      for (int r = 0; r < 2; r++) {
        float4 ov = *(const float4*)&o_s[rh * 2 + r][i4];
        acc[r] += ov.x * w0 + ov.y * w1 + ov.z * w2 + ov.w * w3;
      }
    }
#pragma unroll
    for (int r = 0; r < 2; r++) q_s[rh * 2 + r][c] += acc[r];
  }
  __syncthreads();
  if (t < 128) {
    const int r = t >> 5, i = t & 31;
    float s1 = 0.f, s2 = 0.f;
#pragma unroll
    for (int k = 0; k < 4; k++) {
      float x = q_s[r][i + 32 * k];
      s1 += x;
      s2 += x * x;
    }
#pragma unroll
    for (int m = 1; m <= 16; m <<= 1) {
      s1 += __shfl_xor(s1, m);
      s2 += __shfl_xor(s2, m);
    }
    float mu = s1 * (1.f / 128.f);
    float var = s2 * (1.f / 128.f) - mu * mu;
    float inv = 1.f / sqrtf(var + 1e-5f);
#pragma unroll
    for (int k = 0; k < 4; k++)
      o_s[r][i + 32 * k] = (q_s[r][i + 32 * k] - mu) * inv;
  }
  __syncthreads();
  {
    float a1[4], a2[4];
#pragma unroll
    for (int r = 0; r < 4; r++) {
      a1[r] = 0.f;
      a2[r] = 0.f;
    }
    for (int i4 = 0; i4 < CA; i4 += 4) {
      float w1v[4], w2v[4];
#pragma unroll
      for (int qq = 0; qq < 4; qq++) {
        w1v[qq] = Wt1[(i4 + qq) * FFD + t];
        w2v[qq] = Wt1[(i4 + qq) * FFD + 256 + t];
      }
#pragma unroll
      for (int r = 0; r < 4; r++) {
        float4 yv = *(const float4*)&o_s[r][i4];
        a1[r] += yv.x * w1v[0] + yv.y * w1v[1] + yv.z * w1v[2] + yv.w * w1v[3];
        a2[r] += yv.x * w2v[0] + yv.y * w2v[1] + yv.z * w2v[2] + yv.w * w2v[3];
      }
    }
#pragma unroll
    for (int r = 0; r < 4; r++) {
      h_s[r][t] = fmaxf(a1[r], 0.f);
      h_s[r][256 + t] = fmaxf(a2[r], 0.f);
    }
  }
  __syncthreads();
  {
    float acc[2] = {0.f, 0.f};
    for (int j4 = 0; j4 < FFD; j4 += 4) {
      float w0 = Wt2[(j4 + 0) * CA + c];
      float w1 = Wt2[(j4 + 1) * CA + c];
      float w2 = Wt2[(j4 + 2) * CA + c];
      float w3 = Wt2[(j4 + 3) * CA + c];
#pragma unroll
      for (int r = 0; r < 2; r++) {
        float4 hv = *(const float4*)&h_s[rh * 2 + r][j4];
        acc[r] += hv.x * w0 + hv.y * w1 + hv.z * w2 + hv.w * w3;
      }
    }
#pragma unroll
    for (int r = 0; r < 2; r++) {
      int l = l0 + rh * 2 + r;
      Qg[l * CA + c] = q_s[rh * 2 + r][c] + acc[r];
    }
  }
}

// ---------------------------------------------------------------------------
// pQ = relu(Q @ Wq_tok) via 16x16x32 f16 MFMA. grid (24 col-tiles, 32),
// 4 waves/block, each wave one 16x16 tile, K=128 in 4 chunks.
__global__ __launch_bounds__(256) void k_tok_mm(
    const float* __restrict__ Qg, const float* __restrict__ Wq_tok,
    float* __restrict__ pQ) {
  const int t = threadIdx.x;
  const int w = t >> 6, lane = t & 63;
  const int q = lane >> 4, j16 = lane & 15;
  const int c0 = blockIdx.x * 16;
  const int r0 = (blockIdx.y * 4 + w) * 16;
  f32x4 acc = {0.f, 0.f, 0.f, 0.f};
#pragma unroll
  for (int kk = 0; kk < 4; kk++) {
    // A frag: Q rows, fp32 -> fp16
    const float* ap = Qg + (r0 + j16) * CA + kk * 32 + q * 8;
    float4 a0 = *(const float4*)ap;
    float4 a1 = *(const float4*)(ap + 4);
    half8 af = {(_Float16)a0.x, (_Float16)a0.y, (_Float16)a0.z, (_Float16)a0.w,
                (_Float16)a1.x, (_Float16)a1.y, (_Float16)a1.z, (_Float16)a1.w};
    // B frag: Wq_tok[k][n], column reads
    half8 bf;
#pragma unroll
    for (int jj = 0; jj < 8; jj++)
      bf[jj] = (_Float16)Wq_tok[(kk * 32 + q * 8 + jj) * CT + c0 + j16];
    acc = __builtin_amdgcn_mfma_f32_16x16x32_f16(af, bf, acc, 0, 0, 0);
  }
#pragma unroll
  for (int r = 0; r < 4; r++)
    pQ[(r0 + q * 4 + r) * CT + c0 + j16] = fmaxf(acc[r], 0.f);
}

// ---------------------------------------------------------------------------
// A_I[i] = mean over atoms of pQ rows (already relu'd). Sorted map.
__global__ __launch_bounds__(384) void k_tok_mean(
    const float* __restrict__ pQ, const int* __restrict__ tok,
    float* __restrict__ A_I) {
  __shared__ int lo_s, hi_s;
  const int i = blockIdx.x;
  const int t = threadIdx.x;
  if (t == 0) {
    int lo = 0, hi = L_ATOMS;
    while (lo < hi) {
      int mid = (lo + hi) >> 1;
      if (tok[mid] < i) lo = mid + 1; else hi = mid;
    }
    lo_s = lo;
    int lo2 = lo, hi2 = L_ATOMS;
    while (lo2 < hi2) {
      int mid = (lo2 + hi2) >> 1;
      if (tok[mid] < i + 1) lo2 = mid + 1; else hi2 = mid;
    }
    hi_s = lo2;
  }
  __syncthreads();
  const int lo = lo_s, hi = hi_s;
  float acc = 0.f;
  for (int a = lo; a < hi; a++) acc += pQ[a * CT + t];
  int cnt = hi - lo;
  A_I[i * CT + t] = cnt > 0 ? acc / (float)cnt : 0.f;
}

// ---------------------------------------------------------------------------
extern "C" void kernel_launch(void* const* d_in, const int* in_sizes, int n_in,
                              void* d_out, int out_size, void* d_ws,
                              size_t ws_size, hipStream_t stream) {
  const float* pos = (const float*)d_in[0];
  const float* charge = (const float*)d_in[1];
  const float* elem = (const float*)d_in[2];
  const float* chars = (const float*)d_in[3];
  const int* uid = (const int*)d_in[4];
  const int* tok = (const int*)d_in[5];
  const float* W_in = (const float*)d_in[6];
  const float* W_d = (const float*)d_in[7];
  const float* W_invd = (const float*)d_in[8];
  const float* W_vm = (const float*)d_in[9];
  const float* W_sl = (const float*)d_in[10];
  const float* W_sm = (const float*)d_in[11];
  const float* Wp1 = (const float*)d_in[12];
  const float* Wp2 = (const float*)d_in[13];
  const float* Wp3 = (const float*)d_in[14];
  const float* Wq_tok = (const float*)d_in[15];
  const float* Wq = (const float*)d_in[16];
  const float* Wk = (const float*)d_in[17];
  const float* Wv = (const float*)d_in[18];
  const float* Wb = (const float*)d_in[19];
  const float* Wo = (const float*)d_in[20];
  const float* Wt1 = (const float*)d_in[21];
  const float* Wt2 = (const float*)d_in[22];

  float* out = (float*)d_out;
  float* A_I = out;                   // 512*384
  float* Qg = out + 196608;           // 2048*128 (working residual stream)
  float* C_Lo = out + 458752;         // 2048*128
  float* P_out = out + 720896;        // 2048*2048*16

  char* ws = (char*)d_ws;
  float* csl = (float*)(ws + 0);                        // 128 KB
  float* csm = (float*)(ws + 131072);                   // 128 KB
  _Float16* q_hd = (_Float16*)(ws + 262144);            // 512 KB
  _Float16* k_hd = (_Float16*)(ws + 262144 + 524288);   // 512 KB
  _Float16* vT_hd = (_Float16*)(ws + 262144 + 2 * 524288);  // 512 KB
  float* o_buf = (float*)(ws + 262144 + 3 * 524288);    // 1 MB
  _Float16* bias_hp = (_Float16*)(ws + 262144 + 3 * 524288 + 1048576);
  // pQ (3 MB) reuses the csl..o_buf region, all dead after the last k_ffn.
  float* pQ = (float*)(ws + 0);
  size_t need =
      262144 + 3 * 524288 + 1048576 + (size_t)NBLK * NHEAD * L_ATOMS * L_ATOMS * 2;
  int use_bias = (ws_size >= need) ? 1 : 0;

  k_cl<<<256, 256, 0, stream>>>(pos, charge, elem, chars, W_in, W_sl, W_sm,
                                C_Lo, Qg, csl, csm);
  k_pair<<<dim3(8, 1024), 256, 0, stream>>>(pos, uid, csl, csm, W_d, W_invd,
                                            W_vm, Wp1, Wp2, Wp3, Wb, P_out,
                                            bias_hp, use_bias);
  for (int b = 0; b < NBLK; b++) {
    k_lnqkv<<<512, 256, 0, stream>>>(Qg, Wq + b * 16384, Wk + b * 16384,
                                     Wv + b * 16384, q_hd, k_hd, vT_hd);
    if (use_bias)
      k_attn<1><<<dim3(128, 4), 256, 0, stream>>>(q_hd, k_hd, vT_hd, bias_hp,
                                                  P_out, Wb, o_buf, b);
    else
      k_attn<0><<<dim3(128, 4), 256, 0, stream>>>(q_hd, k_hd, vT_hd, bias_hp,
                                                  P_out, Wb, o_buf, b);
    k_ffn<<<512, 256, 0, stream>>>(Qg, o_buf, Wo + b * 16384, Wt1 + b * 65536,
                                   Wt2 + b * 65536);
  }
  k_tok_mm<<<dim3(24, 32), 256, 0, stream>>>(Qg, Wq_tok, pQ);
  k_tok_mean<<<512, 384, 0, stream>>>(pQ, tok, A_I);
}

// Round 4
// 650.765 us; speedup vs baseline: 1.3129x; 1.1497x over previous
//
#include <hip/hip_runtime.h>
#include <hip/hip_bf16.h>
#include <hip/hip_fp16.h>

#define L_ATOMS 2048
#define N_TOK 512
#define CA 128
#define CP 16
#define CT 384
#define NBLK 3
#define NHEAD 4
#define HDIM 32
#define FFD 512
#define F1D 388

typedef _Float16 half8 __attribute__((ext_vector_type(8)));
typedef _Float16 half4_t __attribute__((ext_vector_type(4)));
typedef float f32x4 __attribute__((ext_vector_type(4)));

// ---------------------------------------------------------------------------
// C_L = feat @ W_in ; Q init = C_L ; csl = relu(C_L)@W_sl ; csm = relu(C_L)@W_sm
// 4 rows/block, grid 512 -> 2 waves/SIMD.
__global__ __launch_bounds__(256) void k_cl(
    const float* __restrict__ pos, const float* __restrict__ charge,
    const float* __restrict__ elem, const float* __restrict__ chars,
    const float* __restrict__ W_in, const float* __restrict__ W_sl,
    const float* __restrict__ W_sm,
    float* __restrict__ out_cl, float* __restrict__ out_q,
    float* __restrict__ csl, float* __restrict__ csm) {
  __shared__ float feat_s[4][F1D];
  __shared__ float rcl_s[4][CA];
  const int t = threadIdx.x;
  const int l0 = blockIdx.x * 4;
  if (t < 12) feat_s[t / 3][t % 3] = pos[l0 * 3 + t];
  else if (t < 16) feat_s[t - 12][3] = charge[l0 + t - 12];
  for (int k = 0; k < 2; k++) {
    int idx = t + k * 256;
    feat_s[idx >> 7][4 + (idx & 127)] = elem[l0 * 128 + idx];
  }
  for (int k = 0; k < 4; k++) {
    int idx = t + k * 256;
    feat_s[idx >> 8][132 + (idx & 255)] = chars[l0 * 256 + idx];
  }
  __syncthreads();
  const int c = t & 127, rh = t >> 7;  // rh 0..1
  float acc[2] = {0.f, 0.f};
  for (int f4 = 0; f4 < F1D; f4 += 4) {  // 388 % 4 == 0
    float w0 = W_in[(f4 + 0) * CA + c];
    float w1 = W_in[(f4 + 1) * CA + c];
    float w2 = W_in[(f4 + 2) * CA + c];
    float w3 = W_in[(f4 + 3) * CA + c];
#pragma unroll
    for (int r = 0; r < 2; r++) {
      float4 fv = *(const float4*)&feat_s[rh * 2 + r][f4];
      acc[r] += fv.x * w0 + fv.y * w1 + fv.z * w2 + fv.w * w3;
    }
  }
#pragma unroll
  for (int r = 0; r < 2; r++) {
    int l = l0 + rh * 2 + r;
    out_cl[l * CA + c] = acc[r];
    out_q[l * CA + c] = acc[r];
    rcl_s[rh * 2 + r][c] = fmaxf(acc[r], 0.f);
  }
  __syncthreads();
  if (t < 128) {
    const int r = t >> 5, j = t & 15, mat = (t >> 4) & 1;
    const float* W = mat ? W_sm : W_sl;
    float a = 0.f;
    for (int i4 = 0; i4 < CA; i4 += 4) {
      float4 xv = *(const float4*)&rcl_s[r][i4];
      a += xv.x * W[i4 * CP + j] + xv.y * W[(i4 + 1) * CP + j] +
           xv.z * W[(i4 + 2) * CP + j] + xv.w * W[(i4 + 3) * CP + j];
    }
    float* dst = mat ? csm : csl;
    dst[(l0 + r) * CP + j] = a;
  }
}

// ---------------------------------------------------------------------------
// k_pair, MFMA version. Transposed chain: X0=relu(P); X1=relu(W1^T X0);
// X2=relu(W2^T X1); P+=W3^T X2; bias=Wb^T P. All via 16x16x16 f16 MFMA.
// (unchanged this round: attribution experiment isolates the attn trio)
__global__ __launch_bounds__(256, 4) void k_pair(
    const float* __restrict__ pos, const int* __restrict__ uid,
    const float* __restrict__ csl, const float* __restrict__ csm,
    const float* __restrict__ W_d, const float* __restrict__ W_invd,
    const float* __restrict__ W_vm, const float* __restrict__ Wp1,
    const float* __restrict__ Wp2, const float* __restrict__ Wp3,
    const float* __restrict__ Wb,
    float* __restrict__ P_out, _Float16* __restrict__ bias_hp, int use_bias) {
  __shared__ _Float16 bias_lds[12 * 2 * 256];  // [plane][lrow][m] 12KB
  const int t = threadIdx.x;
  const int w = t >> 6, lane = t & 63;
  const int q = lane >> 4, j16 = lane & 15;
  const int c4 = q * 4;
  const int m_base = blockIdx.x * 256;
  const int l0 = blockIdx.y * 2;
  // weight A-fragments: A[m=j16][k=c4+r]
  half4_t w1f, w2f, w3f, wbf;
#pragma unroll
  for (int r = 0; r < 4; r++) {
    w1f[r] = (_Float16)Wp1[(c4 + r) * 16 + j16];
    w2f[r] = (_Float16)Wp2[(c4 + r) * 16 + j16];
    w3f[r] = (_Float16)Wp3[(c4 + r) * 16 + j16];
  }
  if (j16 < 12) {
    int bb = j16 >> 2, hh = j16 & 3;
#pragma unroll
    for (int r = 0; r < 4; r++)
      wbf[r] = (_Float16)Wb[(bb * 16 + c4 + r) * 4 + hh];
  } else {
    wbf = half4_t{0, 0, 0, 0};
  }
  // geometry weight columns for this lane's 4 channels
  const float4 wdx = *(const float4*)(W_d + c4);
  const float4 wdy = *(const float4*)(W_d + 16 + c4);
  const float4 wdz = *(const float4*)(W_d + 32 + c4);
  const float4 wiv = *(const float4*)(W_invd + c4);
  const float4 wvm = *(const float4*)(W_vm + c4);
  const float4 cl[2] = {*(const float4*)(csl + l0 * 16 + c4),
                        *(const float4*)(csl + (l0 + 1) * 16 + c4)};
  const float plx[2] = {pos[l0 * 3 + 0], pos[(l0 + 1) * 3 + 0]};
  const float ply[2] = {pos[l0 * 3 + 1], pos[(l0 + 1) * 3 + 1]};
  const float plz[2] = {pos[l0 * 3 + 2], pos[(l0 + 1) * 3 + 2]};
  const int uidl[2] = {uid[l0], uid[l0 + 1]};
  const f32x4 z = {0.f, 0.f, 0.f, 0.f};
#pragma unroll
  for (int it = 0; it < 4; it++) {
    const int moff = w * 64 + it * 16 + j16;
    const int m = m_base + moff;
    const float pmx = pos[m * 3 + 0], pmy = pos[m * 3 + 1],
                pmz = pos[m * 3 + 2];
    const int um = uid[m];
    const float4 cm = *(const float4*)(csm + m * 16 + c4);
#pragma unroll
    for (int li = 0; li < 2; li++) {
      const int lg = l0 + li;
      float dx = plx[li] - pmx, dy = ply[li] - pmy, dz = plz[li] - pmz;
      float vfm = (uidl[li] == um) ? 1.f : 0.f;
      float d2 = dx * dx + dy * dy + dz * dz;
      float invd_v =
          vfm * __builtin_amdgcn_rcpf(1.f + __builtin_amdgcn_sqrtf(d2));
      float dxv = dx * vfm, dyv = dy * vfm, dzv = dz * vfm;
      float pv[4];
      pv[0] = dxv * wdx.x + dyv * wdy.x + dzv * wdz.x + invd_v * wiv.x +
              vfm * wvm.x + cl[li].x + cm.x;
      pv[1] = dxv * wdx.y + dyv * wdy.y + dzv * wdz.y + invd_v * wiv.y +
              vfm * wvm.y + cl[li].y + cm.y;
      pv[2] = dxv * wdx.z + dyv * wdy.z + dzv * wdz.z + invd_v * wiv.z +
              vfm * wvm.z + cl[li].z + cm.z;
      pv[3] = dxv * wdx.w + dyv * wdy.w + dzv * wdz.w + invd_v * wiv.w +
              vfm * wvm.w + cl[li].w + cm.w;
      half4_t b0, b1, b2;
#pragma unroll
      for (int r = 0; r < 4; r++) b0[r] = (_Float16)fmaxf(pv[r], 0.f);
      f32x4 d = __builtin_amdgcn_mfma_f32_16x16x16f16(w1f, b0, z, 0, 0, 0);
#pragma unroll
      for (int r = 0; r < 4; r++) b1[r] = (_Float16)fmaxf(d[r], 0.f);
      d = __builtin_amdgcn_mfma_f32_16x16x16f16(w2f, b1, z, 0, 0, 0);
#pragma unroll
      for (int r = 0; r < 4; r++) b2[r] = (_Float16)fmaxf(d[r], 0.f);
      d = __builtin_amdgcn_mfma_f32_16x16x16f16(w3f, b2, z, 0, 0, 0);
      float pf[4];
#pragma unroll
      for (int r = 0; r < 4; r++) pf[r] = pv[r] + d[r];
      *(float4*)(P_out + ((size_t)lg * L_ATOMS + m) * 16 + c4) =
          make_float4(pf[0], pf[1], pf[2], pf[3]);
      if (use_bias) {
        half4_t bf;
#pragma unroll
        for (int r = 0; r < 4; r++) bf[r] = (_Float16)pf[r];
        f32x4 db = __builtin_amdgcn_mfma_f32_16x16x16f16(wbf, bf, z, 0, 0, 0);
        if (q < 3) {
#pragma unroll
          for (int r = 0; r < 4; r++)
            bias_lds[((q * 4 + r) * 2 + li) * 256 + moff] = (_Float16)db[r];
        }
      }
    }
  }
  if (use_bias) {
    __syncthreads();
    const size_t plane = (size_t)L_ATOMS * L_ATOMS;
#pragma unroll
    for (int kk = 0; kk < 3; kk++) {
      int cid = t + kk * 256;           // 768 chunks of 8 halves
      int pl = cid >> 6;                // 12 planes
      int lrow = (cid >> 5) & 1;
      int chunk = cid & 31;
      half8 v = *(const half8*)&bias_lds[(pl * 2 + lrow) * 256 + chunk * 8];
      *(half8*)(bias_hp + pl * plane + (size_t)(l0 + lrow) * L_ATOMS + m_base +
                chunk * 8) = v;
    }
  }
}

// ---------------------------------------------------------------------------
// x = LN(Q); q/k (head-major fp16), v transposed vT[h][d][l] fp16.
// 4 rows/block, 512 threads (one row per rh-group) -> 4 waves/SIMD.
__global__ __launch_bounds__(512, 4) void k_lnqkv(
    const float* __restrict__ Qg, const float* __restrict__ Wq,
    const float* __restrict__ Wk, const float* __restrict__ Wv,
    _Float16* __restrict__ q_hd, _Float16* __restrict__ k_hd,
    _Float16* __restrict__ vT_hd) {
  __shared__ float x_s[4][CA];
  const int t = threadIdx.x;
  const int l0 = blockIdx.x * 4;
  if (t < 128) ((float4*)x_s)[t] = ((const float4*)(Qg + l0 * CA))[t];
  __syncthreads();
  if (t < 128) {
    const int r = t >> 5, i = t & 31;
    float s1 = 0.f, s2 = 0.f;
#pragma unroll
    for (int k = 0; k < 4; k++) {
      float x = x_s[r][i + 32 * k];
      s1 += x;
      s2 += x * x;
    }
#pragma unroll
    for (int m = 1; m <= 16; m <<= 1) {
      s1 += __shfl_xor(s1, m);
      s2 += __shfl_xor(s2, m);
    }
    float mu = s1 * (1.f / 128.f);
    float var = s2 * (1.f / 128.f) - mu * mu;
    float inv = 1.f / sqrtf(var + 1e-5f);
#pragma unroll
    for (int k = 0; k < 4; k++)
      x_s[r][i + 32 * k] = (x_s[r][i + 32 * k] - mu) * inv;
  }
  __syncthreads();
  const int c = t & 127, rh = t >> 7;  // rh 0..3: one row each
  const int h = c >> 5, d = c & 31;
  const int l = l0 + rh;
#pragma unroll
  for (int mat = 0; mat < 3; mat++) {
    const float* W = mat == 0 ? Wq : (mat == 1 ? Wk : Wv);
    float acc = 0.f;
    for (int i4 = 0; i4 < CA; i4 += 4) {
      float w0 = W[(i4 + 0) * CA + c];
      float w1 = W[(i4 + 1) * CA + c];
      float w2 = W[(i4 + 2) * CA + c];
      float w3 = W[(i4 + 3) * CA + c];
      float4 xv = *(const float4*)&x_s[rh][i4];
      acc += xv.x * w0 + xv.y * w1 + xv.z * w2 + xv.w * w3;
    }
    if (mat == 0)
      q_hd[(h * L_ATOMS + l) * HDIM + d] = (_Float16)acc;
    else if (mat == 1)
      k_hd[(h * L_ATOMS + l) * HDIM + d] = (_Float16)acc;
    else
      vT_hd[(h * HDIM + d) * L_ATOMS + l] = (_Float16)acc;
  }
}

// ---------------------------------------------------------------------------
// flash attention, one (16-row l-tile, head) per block; 8 waves split m-range
// (256 m each, 8 iters) -> 4 waves/SIMD and half-length serial chains.
// Transposed logits: D = mfma(K, Q) -> D[row=m][col=l]. p_lds is per-wave:
// no barriers in the main loop.
template <int USE_BIAS>
__global__ __launch_bounds__(512, 4) void k_attn(
    const _Float16* __restrict__ q_hd, const _Float16* __restrict__ k_hd,
    const _Float16* __restrict__ vT_hd, const _Float16* __restrict__ bias_hp,
    const float* __restrict__ Pmat, const float* __restrict__ Wb,
    float* __restrict__ o_buf, int b) {
  __shared__ __align__(16) _Float16 p_lds[8][16][40];  // [wave][l][m]
  __shared__ float o_sh[8][16][33];
  __shared__ float M_sh[8][16];
  __shared__ float S_sh[8][16];
  __shared__ float wb_s[16];
  const int t = threadIdx.x;
  const int w = t >> 6, lane = t & 63;
  const int l0 = blockIdx.x * 16;
  const int h = blockIdx.y;
  if (USE_BIAS == 0) {
    if (t < 16) wb_s[t] = Wb[(b * 16 + t) * 4 + h];
    __syncthreads();
  }
  const int c16 = lane & 15, q4 = lane >> 4;
  // B-operand: q row l = l0 + c16
  half8 qa = *(const half8*)(q_hd + ((h * L_ATOMS + l0 + c16) * HDIM + q4 * 8));
  f32x4 o0 = {0.f, 0.f, 0.f, 0.f}, o1 = {0.f, 0.f, 0.f, 0.f};
  float M = -INFINITY;  // running max for row l = l0+c16 (dup across quads)
  float S = 0.f;
  const float scale = 0.17677669529663687f;  // 1/sqrt(32)
  const _Float16* bias_row =
      bias_hp + ((size_t)(b * 4 + h) * L_ATOMS + (l0 + c16)) * L_ATOMS;
  for (int it = 0; it < 8; it++) {
    const int m0 = w * 256 + it * 32;
    half8 kb0 =
        *(const half8*)(k_hd + ((h * L_ATOMS + m0 + c16) * HDIM + q4 * 8));
    half8 kb1 =
        *(const half8*)(k_hd + ((h * L_ATOMS + m0 + 16 + c16) * HDIM + q4 * 8));
    half8 vb0 =
        *(const half8*)(vT_hd + ((h * HDIM + c16) * L_ATOMS + m0 + q4 * 8));
    half8 vb1 = *(const half8*)(vT_hd +
                                ((h * HDIM + 16 + c16) * L_ATOMS + m0 + q4 * 8));
    f32x4 z = {0.f, 0.f, 0.f, 0.f};
    f32x4 c0 = __builtin_amdgcn_mfma_f32_16x16x32_f16(kb0, qa, z, 0, 0, 0);
    f32x4 c1 = __builtin_amdgcn_mfma_f32_16x16x32_f16(kb1, qa, z, 0, 0, 0);
    float l0v[4], l1v[4];
    if (USE_BIAS) {
      half4_t bh0 = *(const half4_t*)(bias_row + m0 + q4 * 4);
      half4_t bh1 = *(const half4_t*)(bias_row + m0 + 16 + q4 * 4);
#pragma unroll
      for (int r = 0; r < 4; r++) {
        l0v[r] = c0[r] * scale + (float)bh0[r];
        l1v[r] = c1[r] * scale + (float)bh1[r];
      }
    } else {
#pragma unroll
      for (int r = 0; r < 4; r++) {
        const float* Pp0 =
            Pmat + ((size_t)(l0 + c16) * L_ATOMS + m0 + q4 * 4 + r) * 16;
        const float* Pp1 = Pp0 + 16 * 16;
        float a0 = 0.f, a1 = 0.f;
#pragma unroll
        for (int c2 = 0; c2 < 16; c2++) {
          a0 += Pp0[c2] * wb_s[c2];
          a1 += Pp1[c2] * wb_s[c2];
        }
        l0v[r] = c0[r] * scale + a0;
        l1v[r] = c1[r] * scale + a1;
      }
    }
    // online softmax over m for row l = l0+c16
    float tm = fmaxf(fmaxf(fmaxf(l0v[0], l0v[1]), fmaxf(l0v[2], l0v[3])),
                     fmaxf(fmaxf(l1v[0], l1v[1]), fmaxf(l1v[2], l1v[3])));
    tm = fmaxf(tm, __shfl_xor(tm, 16));
    tm = fmaxf(tm, __shfl_xor(tm, 32));
    float Mn = fmaxf(M, tm);
    float al = __expf(M - Mn);
    float p0[4], p1[4], ps = 0.f;
#pragma unroll
    for (int r = 0; r < 4; r++) {
      p0[r] = __expf(l0v[r] - Mn);
      p1[r] = __expf(l1v[r] - Mn);
      ps += p0[r] + p1[r];
    }
    float rs = ps + __shfl_xor(ps, 16);
    rs += __shfl_xor(rs, 32);
    S = S * al + rs;
    M = Mn;
    // P -> LDS [l][m], two 8B stores
    half4_t ph0, ph1;
#pragma unroll
    for (int r = 0; r < 4; r++) {
      ph0[r] = (_Float16)p0[r];
      ph1[r] = (_Float16)p1[r];
    }
    *(half4_t*)&p_lds[w][c16][q4 * 4] = ph0;
    *(half4_t*)&p_lds[w][c16][16 + q4 * 4] = ph1;
    // rescale O rows (row index = q4*4+r) with that row's al
    float alr[4];
#pragma unroll
    for (int r = 0; r < 4; r++) alr[r] = __shfl(al, q4 * 4 + r);
#pragma unroll
    for (int r = 0; r < 4; r++) {
      o0[r] *= alr[r];
      o1[r] *= alr[r];
    }
    asm volatile("" ::: "memory");
    __builtin_amdgcn_sched_barrier(0);
    half8 pa = *(const half8*)(&p_lds[w][c16][q4 * 8]);
    o0 = __builtin_amdgcn_mfma_f32_16x16x32_f16(pa, vb0, o0, 0, 0, 0);
    o1 = __builtin_amdgcn_mfma_f32_16x16x32_f16(pa, vb1, o1, 0, 0, 0);
    asm volatile("" ::: "memory");
    __builtin_amdgcn_sched_barrier(0);
  }
#pragma unroll
  for (int r = 0; r < 4; r++) {
    o_sh[w][q4 * 4 + r][c16] = o0[r];
    o_sh[w][q4 * 4 + r][16 + c16] = o1[r];
  }
  if (q4 == 0) {
    M_sh[w][c16] = M;
    S_sh[w][c16] = S;
  }
  __syncthreads();
  {
    const int d = t & 31, row = t >> 5;  // 512 threads: one (row, d) each
    float Mg = M_sh[0][row];
#pragma unroll
    for (int ww = 1; ww < 8; ww++) Mg = fmaxf(Mg, M_sh[ww][row]);
    float Sg = 0.f, ov = 0.f;
#pragma unroll
    for (int ww = 0; ww < 8; ww++) {
      float e = __expf(M_sh[ww][row] - Mg);
      Sg += S_sh[ww][row] * e;
      ov += o_sh[ww][row][d] * e;
    }
    o_buf[(l0 + row) * CA + h * HDIM + d] = ov / Sg;
  }
}

// ---------------------------------------------------------------------------
// Q += o@Wo ; y = LN(Q) ; Q += relu(y@Wt1)@Wt2.
// 4 rows/block, 512 threads -> 4 waves/SIMD.
__global__ __launch_bounds__(512, 4) void k_ffn(
    float* __restrict__ Qg, const float* __restrict__ o_buf,
    const float* __restrict__ Wo, const float* __restrict__ Wt1,
    const float* __restrict__ Wt2) {
  __shared__ float o_s[4][CA];
  __shared__ float q_s[4][CA];
  __shared__ float h_s[4][FFD];
  const int t = threadIdx.x;
  const int l0 = blockIdx.x * 4;
  if (t < 128) {
    ((float4*)o_s)[t] = ((const float4*)(o_buf + l0 * CA))[t];
    ((float4*)q_s)[t] = ((const float4*)(Qg + l0 * CA))[t];
  }
  __syncthreads();
  const int c = t & 127, rh = t >> 7;  // rh 0..3: one row each
  {
    float acc = 0.f;
    for (int i4 = 0; i4 < CA; i4 += 4) {
      float w0 = Wo[(i4 + 0) * CA + c];
      float w1 = Wo[(i4 + 1) * CA + c];
      float w2 = Wo[(i4 + 2) * CA + c];
      float w3 = Wo[(i4 + 3) * CA + c];
      float4 ov = *(const float4*)&o_s[rh][i4];
      acc += ov.x * w0 + ov.y * w1 + ov.z * w2 + ov.w * w3;
    }
    q_s[rh][c] += acc;
  }
  __syncthreads();
  if (t < 128) {
    const int r = t >> 5, i = t & 31;
    float s1 = 0.f, s2 = 0.f;
#pragma unroll
    for (int k = 0; k < 4; k++) {
      float x = q_s[r][i + 32 * k];
      s1 += x;
      s2 += x * x;
    }
#pragma unroll
    for (int m = 1; m <= 16; m <<= 1) {
      s1 += __shfl_xor(s1, m);
      s2 += __shfl_xor(s2, m);
    }
    float mu = s1 * (1.f / 128.f);
    float var = s2 * (1.f / 128.f) - mu * mu;
    float inv = 1.f / sqrtf(var + 1e-5f);
#pragma unroll
    for (int k = 0; k < 4; k++)
      o_s[r][i + 32 * k] = (q_s[r][i + 32 * k] - mu) * inv;
  }
  __syncthreads();
  {
    float a[4] = {0.f, 0.f, 0.f, 0.f};
    for (int i4 = 0; i4 < CA; i4 += 4) {
      float wv[4];
#pragma unroll
      for (int qq = 0; qq < 4; qq++) wv[qq] = Wt1[(i4 + qq) * FFD + t];
#pragma unroll
      for (int r = 0; r < 4; r++) {
        float4 yv = *(const float4*)&o_s[r][i4];
        a[r] += yv.x * wv[0] + yv.y * wv[1] + yv.z * wv[2] + yv.w * wv[3];
      }
    }
#pragma unroll
    for (int r = 0; r < 4; r++) h_s[r][t] = fmaxf(a[r], 0.f);
  }
  __syncthreads();
  {
    float acc = 0.f;
    for (int j4 = 0; j4 < FFD; j4 += 4) {
      float w0 = Wt2[(j4 + 0) * CA + c];
      float w1 = Wt2[(j4 + 1) * CA + c];
      float w2 = Wt2[(j4 + 2) * CA + c];
      float w3 = Wt2[(j4 + 3) * CA + c];
      float4 hv = *(const float4*)&h_s[rh][j4];
      acc += hv.x * w0 + hv.y * w1 + hv.z * w2 + hv.w * w3;
    }
    Qg[(l0 + rh) * CA + c] = q_s[rh][c] + acc;
  }
}

// ---------------------------------------------------------------------------
// pQ = relu(Q @ Wq_tok) via 16x16x32 f16 MFMA. grid (24 col-tiles, 32),
// 4 waves/block, each wave one 16x16 tile, K=128 in 4 chunks.
__global__ __launch_bounds__(256) void k_tok_mm(
    const float* __restrict__ Qg, const float* __restrict__ Wq_tok,
    float* __restrict__ pQ) {
  const int t = threadIdx.x;
  const int w = t >> 6, lane = t & 63;
  const int q = lane >> 4, j16 = lane & 15;
  const int c0 = blockIdx.x * 16;
  const int r0 = (blockIdx.y * 4 + w) * 16;
  f32x4 acc = {0.f, 0.f, 0.f, 0.f};
#pragma unroll
  for (int kk = 0; kk < 4; kk++) {
    // A frag: Q rows, fp32 -> fp16
    const float* ap = Qg + (r0 + j16) * CA + kk * 32 + q * 8;
    float4 a0 = *(const float4*)ap;
    float4 a1 = *(const float4*)(ap + 4);
    half8 af = {(_Float16)a0.x, (_Float16)a0.y, (_Float16)a0.z, (_Float16)a0.w,
                (_Float16)a1.x, (_Float16)a1.y, (_Float16)a1.z, (_Float16)a1.w};
    // B frag: Wq_tok[k][n], column reads
    half8 bf;
#pragma unroll
    for (int jj = 0; jj < 8; jj++)
      bf[jj] = (_Float16)Wq_tok[(kk * 32 + q * 8 + jj) * CT + c0 + j16];
    acc = __builtin_amdgcn_mfma_f32_16x16x32_f16(af, bf, acc, 0, 0, 0);
  }
#pragma unroll
  for (int r = 0; r < 4; r++)
    pQ[(r0 + q * 4 + r) * CT + c0 + j16] = fmaxf(acc[r], 0.f);
}

// ---------------------------------------------------------------------------
// A_I[i] = mean over atoms of pQ rows (already relu'd). Sorted map.
__global__ __launch_bounds__(384) void k_tok_mean(
    const float* __restrict__ pQ, const int* __restrict__ tok,
    float* __restrict__ A_I) {
  __shared__ int lo_s, hi_s;
  const int i = blockIdx.x;
  const int t = threadIdx.x;
  if (t == 0) {
    int lo = 0, hi = L_ATOMS;
    while (lo < hi) {
      int mid = (lo + hi) >> 1;
      if (tok[mid] < i) lo = mid + 1; else hi = mid;
    }
    lo_s = lo;
    int lo2 = lo, hi2 = L_ATOMS;
    while (lo2 < hi2) {
      int mid = (lo2 + hi2) >> 1;
      if (tok[mid] < i + 1) lo2 = mid + 1; else hi2 = mid;
    }
    hi_s = lo2;
  }
  __syncthreads();
  const int lo = lo_s, hi = hi_s;
  float acc = 0.f;
  for (int a = lo; a < hi; a++) acc += pQ[a * CT + t];
  int cnt = hi - lo;
  A_I[i * CT + t] = cnt > 0 ? acc / (float)cnt : 0.f;
}

// ---------------------------------------------------------------------------
extern "C" void kernel_launch(void* const* d_in, const int* in_sizes, int n_in,
                              void* d_out, int out_size, void* d_ws,
                              size_t ws_size, hipStream_t stream) {
  const float* pos = (const float*)d_in[0];
  const float* charge = (const float*)d_in[1];
  const float* elem = (const float*)d_in[2];
  const float* chars = (const float*)d_in[3];
  const int* uid = (const int*)d_in[4];
  const int* tok = (const int*)d_in[5];
  const float* W_in = (const float*)d_in[6];
  const float* W_d = (const float*)d_in[7];
  const float* W_invd = (const float*)d_in[8];
  const float* W_vm = (const float*)d_in[9];
  const float* W_sl = (const float*)d_in[10];
  const float* W_sm = (const float*)d_in[11];
  const float* Wp1 = (const float*)d_in[12];
  const float* Wp2 = (const float*)d_in[13];
  const float* Wp3 = (const float*)d_in[14];
  const float* Wq_tok = (const float*)d_in[15];
  const float* Wq = (const float*)d_in[16];
  const float* Wk = (const float*)d_in[17];
  const float* Wv = (const float*)d_in[18];
  const float* Wb = (const float*)d_in[19];
  const float* Wo = (const float*)d_in[20];
  const float* Wt1 = (const float*)d_in[21];
  const float* Wt2 = (const float*)d_in[22];

  float* out = (float*)d_out;
  float* A_I = out;                   // 512*384
  float* Qg = out + 196608;           // 2048*128 (working residual stream)
  float* C_Lo = out + 458752;         // 2048*128
  float* P_out = out + 720896;        // 2048*2048*16

  char* ws = (char*)d_ws;
  float* csl = (float*)(ws + 0);                        // 128 KB
  float* csm = (float*)(ws + 131072);                   // 128 KB
  _Float16* q_hd = (_Float16*)(ws + 262144);            // 512 KB
  _Float16* k_hd = (_Float16*)(ws + 262144 + 524288);   // 512 KB
  _Float16* vT_hd = (_Float16*)(ws + 262144 + 2 * 524288);  // 512 KB
  float* o_buf = (float*)(ws + 262144 + 3 * 524288);    // 1 MB
  _Float16* bias_hp = (_Float16*)(ws + 262144 + 3 * 524288 + 1048576);
  // pQ (3 MB) reuses the csl..o_buf region, all dead after the last k_ffn.
  float* pQ = (float*)(ws + 0);
  size_t need =
      262144 + 3 * 524288 + 1048576 + (size_t)NBLK * NHEAD * L_ATOMS * L_ATOMS * 2;
  int use_bias = (ws_size >= need) ? 1 : 0;

  k_cl<<<512, 256, 0, stream>>>(pos, charge, elem, chars, W_in, W_sl, W_sm,
                                C_Lo, Qg, csl, csm);
  k_pair<<<dim3(8, 1024), 256, 0, stream>>>(pos, uid, csl, csm, W_d, W_invd,
                                            W_vm, Wp1, Wp2, Wp3, Wb, P_out,
                                            bias_hp, use_bias);
  for (int b = 0; b < NBLK; b++) {
    k_lnqkv<<<512, 512, 0, stream>>>(Qg, Wq + b * 16384, Wk + b * 16384,
                                     Wv + b * 16384, q_hd, k_hd, vT_hd);
    if (use_bias)
      k_attn<1><<<dim3(128, 4), 512, 0, stream>>>(q_hd, k_hd, vT_hd, bias_hp,
                                                  P_out, Wb, o_buf, b);
    else
      k_attn<0><<<dim3(128, 4), 512, 0, stream>>>(q_hd, k_hd, vT_hd, bias_hp,
                                                  P_out, Wb, o_buf, b);
    k_ffn<<<512, 512, 0, stream>>>(Qg, o_buf, Wo + b * 16384, Wt1 + b * 65536,
                                   Wt2 + b * 65536);
  }
  k_tok_mm<<<dim3(24, 32), 256, 0, stream>>>(Qg, Wq_tok, pQ);
  k_tok_mean<<<512, 384, 0, stream>>>(pQ, tok, A_I);
}